// Round 6
// baseline (584.897 us; speedup 1.0000x reference)
//
#include <hip/hip_runtime.h>
#include <stdint.h>

// Problem constants (fixed for this instance)
#define IN_C   128
#define HID_C  128
#define NREL   8
#define K_TOTAL (NREL * IN_C)   // 1024
#define K_HALF 512              // MFMA processed in two K-rounds over one S
#define TILE_M  16              // nodes per block
#define SRB_H   520             // bf16 units per node row in LDS (512 + 8 pad)

typedef float  f32x4  __attribute__((ext_vector_type(4)));
typedef __bf16 bf16x8 __attribute__((ext_vector_type(8)));
typedef short  s16x8 __attribute__((ext_vector_type(8)));
typedef unsigned short u16;

__device__ __forceinline__ unsigned short f2bf(float f) {
    unsigned int u = __float_as_uint(f);
    u += 0x7fffu + ((u >> 16) & 1u);   // round-to-nearest-even
    return (unsigned short)(u >> 16);
}

__global__ void zero_count_kernel(unsigned int* count) { *count = 0u; }

// ---------------- prep (fused): compute-node list + packed meta + W->bf16
//                  transpose + history copy.
__global__ __launch_bounds__(256) void prep_kernel(
        const float* __restrict__ W,
        const int* __restrict__ hmap, const float* __restrict__ hbuf,
        const int* __restrict__ ptr, const int* __restrict__ idx,
        const int* __restrict__ ety,
        unsigned short* __restrict__ Wt,
        int4* __restrict__ list2, unsigned* __restrict__ emeta,
        unsigned int* __restrict__ count,
        float* __restrict__ out, int NN, int WE) {
    int gid = blockIdx.x * blockDim.x + threadIdx.x;

    // compact list of compute nodes (wave-aggregated atomics). No early
    // returns above this point: all lanes must reach the ballot.
    {
        bool active = (gid < NN) && (hmap[gid] == -1);
        unsigned long long mask = __ballot(active);
        if (mask) {
            int lane   = threadIdx.x & 63;
            int leader = __ffsll((unsigned long long)mask) - 1;
            unsigned base = 0;
            if (lane == leader) base = atomicAdd(count, (unsigned)__popcll(mask));
            base = __shfl(base, leader, 64);
            if (active) {
                int off = __popcll(mask & ((1ull << lane) - 1ull));
                int p   = (int)base + off;
                int e0  = ptr[gid], e1 = ptr[gid + 1];
                int d   = e1 - e0;
                list2[p] = int4{gid, e0, d, 0};
                #pragma unroll
                for (int j = 0; j < 16; ++j) {
                    unsigned m = 0xFFFFFFFFu;
                    if (j < d) {
                        int e = e0 + j;
                        m = ((unsigned)idx[e]) | (((unsigned)ety[e]) << 27);
                    }
                    emeta[(size_t)p * 16 + j] = m;
                }
            }
        }
    }

    // per (node, f32x4-chunk): history-row copy to both output halves
    int n = gid >> 5;           // node
    int q = gid & 31;           // f32x4 index within 128-float row
    if (n < NN) {
        if (hmap[n] != -1) {
            f32x4 v = ((const f32x4*)hbuf)[(size_t)n * 32 + q];
            f32x4* o = (f32x4*)out;
            o[(size_t)n * 32 + q] = v;
            o[(size_t)NN * 32 + (size_t)n * 32 + q] = v;
        }
    }

    // W[r][k][c] -> Wt[c][r*128+k] in bf16
    if (gid < WE) {
        int r   = gid >> 14;      // / (128*128)
        int rem = gid & 16383;
        int k   = rem >> 7;       // / 128
        int c   = rem & 127;
        Wt[(size_t)c * K_TOTAL + r * IN_C + k] = f2bf(W[gid]);
    }
}

// ---------------- fused gather + bf16 MFMA GEMM, half-LDS / 8-blocks-per-CU
// K=1024 processed as two K=512 rounds over ONE 16.6 KB S tile, so total
// LDS ~17.9 KB -> 8 blocks/CU (was 34.3 KB -> 4). Accum identical to R4.
__global__ __launch_bounds__(256, 8) void gemm_kernel(
        const float* __restrict__ x,
        const int* __restrict__ idx,
        const int* __restrict__ ety,
        const unsigned short* __restrict__ Wt,
        const int4* __restrict__ list2,
        const unsigned* __restrict__ emeta,
        const unsigned int* __restrict__ count,
        float* __restrict__ out, int NN) {
    __shared__ u16      S[TILE_M * SRB_H];    // 16640 B, bf16 half-K A-tile
    __shared__ int      nids[TILE_M];
    __shared__ int      e0s[TILE_M];
    __shared__ int      degs[TILE_M];
    __shared__ float    invdeg[TILE_M];
    __shared__ unsigned meta_x[256];          // extension path (deg>16) only

    unsigned int cnt = *count;
    int rowbase = blockIdx.x * TILE_M;
    if (rowbase >= (int)cnt) return;          // uniform exit, before any barrier

    int t = threadIdx.x;
    int n = t >> 4;            // node slot 0..15
    int c = t & 15;            // 8-float channel chunk 0..15
    int lane = t & 63;

    // hop 1: coalesced meta load (no dependent chain)
    bool vrow = (rowbase + n) < (int)cnt;
    unsigned mymeta = vrow ? emeta[(size_t)rowbase * 16 + t] : 0xFFFFFFFFu;

    // independent: per-tile node info into LDS (consumed after B1)
    if (t < TILE_M) {
        int nid = -1, e0 = 0, d = 0; float idg = 0.f;
        if (rowbase + t < (int)cnt) {
            int4 L = list2[rowbase + t];
            nid = L.x; e0 = L.y; d = L.z;
            idg = (d > 0) ? 1.0f / (float)d : 0.f;
        }
        nids[t] = nid; e0s[t] = e0; degs[t] = d; invdeg[t] = idg;
    }

    // distribute the 16 metas of node n across its 16 threads (intra-wave)
    unsigned mm[16];
    #pragma unroll
    for (int j = 0; j < 16; ++j)
        mm[j] = __shfl(mymeta, (lane & 48) | j, 64);

    int offs[16];   // element offset of this thread's chunk in x
    int rel[16];    // relation id, 31 = inactive (one-hot never matches)
    #pragma unroll
    for (int j = 0; j < 16; ++j) {
        unsigned m = mm[j];
        bool valid = (m != 0xFFFFFFFFu);
        int src = valid ? (int)(m & 0x07FFFFFFu) : 0;
        rel[j]  = valid ? (int)(m >> 27) : 31;
        offs[j] = src * IN_C;
    }

    // per-thread accumulator: 8 relations x 8 channels (64 VGPRs)
    f32x4 alo[NREL], ahi[NREL];
    #pragma unroll
    for (int r = 0; r < NREL; ++r) { alo[r] = f32x4{0,0,0,0}; ahi[r] = f32x4{0,0,0,0}; }

    const float* xc = x + c * 8;   // channel-chunk base

    // gather, 4-edge batches, double-buffered (8 edges in flight)
    {
        f32x4 blo[4], bhi[4];
        #pragma unroll
        for (int u = 0; u < 4; ++u) {
            const f32x4* p = (const f32x4*)(xc + offs[u]);
            blo[u] = p[0]; bhi[u] = p[1];
        }
        #pragma unroll
        for (int b = 0; b < 4; ++b) {
            f32x4 nlo[4], nhi[4];
            if (b < 3) {
                #pragma unroll
                for (int u = 0; u < 4; ++u) {
                    const f32x4* p = (const f32x4*)(xc + offs[(b + 1) * 4 + u]);
                    nlo[u] = p[0]; nhi[u] = p[1];
                }
            }
            #pragma unroll
            for (int u = 0; u < 4; ++u) {
                int r = rel[b * 4 + u];
                #pragma unroll
                for (int rr = 0; rr < NREL; ++rr) {       // branchless one-hot
                    float mk = (r == rr) ? 1.0f : 0.0f;
                    alo[rr] += blo[u] * mk;
                    ahi[rr] += bhi[u] * mk;
                }
            }
            if (b < 3) {
                #pragma unroll
                for (int u = 0; u < 4; ++u) { blo[u] = nlo[u]; bhi[u] = nhi[u]; }
            }
        }
    }
    __syncthreads();   // B1: nids/degs/invdeg visible

    // rare general path: any node with deg > 16 (block-uniform branch)
    int md = 0;
    #pragma unroll
    for (int i = 0; i < TILE_M; ++i) md = max(md, degs[i]);
    if (md > TILE_M) {
        int nid_n = nids[n], deg_n = degs[n], e0_n = e0s[n];
        for (int jb = TILE_M; jb < md; jb += TILE_M) {
            {
                int j = jb + c;
                unsigned m = 0xFFFFFFFFu;
                if (nid_n >= 0 && j < deg_n) {
                    int e = e0_n + j;
                    m = ((unsigned)idx[e]) | (((unsigned)ety[e]) << 27);
                }
                meta_x[t] = m;
            }
            __syncthreads();
            uint4 q0 = *(const uint4*)(meta_x + (n << 4) + 0);
            uint4 q1 = *(const uint4*)(meta_x + (n << 4) + 4);
            uint4 q2 = *(const uint4*)(meta_x + (n << 4) + 8);
            uint4 q3 = *(const uint4*)(meta_x + (n << 4) + 12);
            unsigned mx[16] = {q0.x,q0.y,q0.z,q0.w, q1.x,q1.y,q1.z,q1.w,
                               q2.x,q2.y,q2.z,q2.w, q3.x,q3.y,q3.z,q3.w};
            #pragma unroll
            for (int j = 0; j < 16; ++j) {
                unsigned m = mx[j];
                bool valid = (m != 0xFFFFFFFFu);
                int src = valid ? (int)(m & 0x07FFFFFFu) : 0;
                int r   = valid ? (int)(m >> 27) : 31;
                const f32x4* p = (const f32x4*)(xc + src * IN_C);
                f32x4 lo = p[0], hi = p[1];
                #pragma unroll
                for (int rr = 0; rr < NREL; ++rr) {
                    float mk = (r == rr) ? 1.0f : 0.0f;
                    alo[rr] += lo * mk;
                    ahi[rr] += hi * mk;
                }
            }
            __syncthreads();
        }
    }

    // MFMA geometry
    int wave = t >> 6;
    int quad = lane >> 4, l16 = lane & 15;
    int chbase = wave * 32;                 // each wave owns 32 output channels
    const u16* arow  = S + l16 * SRB_H + quad * 8;
    const u16* bbase = Wt + (size_t)(chbase + l16) * K_TOTAL + quad * 8;
    u16* srow = S + n * SRB_H + c * 8;

    f32x4 acc0 = {0.f,0.f,0.f,0.f};
    f32x4 acc1 = {0.f,0.f,0.f,0.f};

    // -------- round A: relations 0..3 -> S, MFMA over K in [0, 512)
    #pragma unroll
    for (int rr = 0; rr < 4; ++rr) {
        s16x8 pk;
        pk[0] = (short)f2bf(alo[rr][0]); pk[1] = (short)f2bf(alo[rr][1]);
        pk[2] = (short)f2bf(alo[rr][2]); pk[3] = (short)f2bf(alo[rr][3]);
        pk[4] = (short)f2bf(ahi[rr][0]); pk[5] = (short)f2bf(ahi[rr][1]);
        pk[6] = (short)f2bf(ahi[rr][2]); pk[7] = (short)f2bf(ahi[rr][3]);
        *(s16x8*)(srow + rr * IN_C) = pk;
    }
    __syncthreads();   // B2: S(relations 0-3) ready
    #pragma unroll 8
    for (int ks = 0; ks < K_HALF; ks += 32) {
        s16x8 a  = *(const s16x8*)(arow + ks);
        s16x8 b0 = *(const s16x8*)(bbase + ks);
        s16x8 b1 = *(const s16x8*)(bbase + ks + 16 * K_TOTAL);
        union { s16x8 s; bf16x8 b; } ua, ub0, ub1;
        ua.s = a; ub0.s = b0; ub1.s = b1;
        acc0 = __builtin_amdgcn_mfma_f32_16x16x32_bf16(ua.b, ub0.b, acc0, 0, 0, 0);
        acc1 = __builtin_amdgcn_mfma_f32_16x16x32_bf16(ua.b, ub1.b, acc1, 0, 0, 0);
    }
    __syncthreads();   // B3: S consumed, safe to overwrite

    // -------- round B: relations 4..7 -> S, MFMA over K in [512, 1024)
    #pragma unroll
    for (int rr = 0; rr < 4; ++rr) {
        s16x8 pk;
        pk[0] = (short)f2bf(alo[rr + 4][0]); pk[1] = (short)f2bf(alo[rr + 4][1]);
        pk[2] = (short)f2bf(alo[rr + 4][2]); pk[3] = (short)f2bf(alo[rr + 4][3]);
        pk[4] = (short)f2bf(ahi[rr + 4][0]); pk[5] = (short)f2bf(ahi[rr + 4][1]);
        pk[6] = (short)f2bf(ahi[rr + 4][2]); pk[7] = (short)f2bf(ahi[rr + 4][3]);
        *(s16x8*)(srow + rr * IN_C) = pk;
    }
    __syncthreads();   // B4: S(relations 4-7) ready
    #pragma unroll 8
    for (int ks = 0; ks < K_HALF; ks += 32) {
        s16x8 a  = *(const s16x8*)(arow + ks);
        s16x8 b0 = *(const s16x8*)(bbase + K_HALF + ks);
        s16x8 b1 = *(const s16x8*)(bbase + K_HALF + ks + 16 * K_TOTAL);
        union { s16x8 s; bf16x8 b; } ua, ub0, ub1;
        ua.s = a; ub0.s = b0; ub1.s = b1;
        acc0 = __builtin_amdgcn_mfma_f32_16x16x32_bf16(ua.b, ub0.b, acc0, 0, 0, 0);
        acc1 = __builtin_amdgcn_mfma_f32_16x16x32_bf16(ua.b, ub1.b, acc1, 0, 0, 0);
    }

    // epilogue: C/D layout col=lane&15, row=(lane>>4)*4+reg  (verified)
    size_t half = (size_t)NN * HID_C;
    #pragma unroll
    for (int v = 0; v < 4; ++v) {
        int rowl = quad * 4 + v;
        int onid = nids[rowl];
        if (onid < 0) continue;
        float s = invdeg[rowl];
        float v0 = acc0[v] * s;
        float v1 = acc1[v] * s;
        size_t o0 = (size_t)onid * HID_C + chbase + l16;
        out[o0]             = v0;
        out[o0 + 16]        = v1;
        out[o0 + half]      = v0;
        out[o0 + 16 + half] = v1;
    }
}

extern "C" void kernel_launch(void* const* d_in, const int* in_sizes, int n_in,
                              void* d_out, int out_size, void* d_ws, size_t ws_size,
                              hipStream_t stream) {
    const float* x    = (const float*)d_in[0];
    const float* W    = (const float*)d_in[1];
    const int*   ptr  = (const int*)d_in[2];
    const int*   idx  = (const int*)d_in[3];
    const int*   ety  = (const int*)d_in[4];
    const int*   hmap = (const int*)d_in[5];
    const float* hbuf = (const float*)d_in[6];
    int NN = in_sizes[5];          // 100000
    int WE = in_sizes[1];          // 8*128*128
    float* out = (float*)d_out;

    // workspace layout: count | list2(int4) | Wt(bf16) | emeta
    unsigned int* count = (unsigned int*)d_ws;
    int4* list2 = (int4*)((char*)d_ws + 256);
    size_t wt_off = 256 + (((size_t)NN * 16 + 4095) / 4096) * 4096;
    unsigned short* Wt = (unsigned short*)((char*)d_ws + wt_off);      // 256 KB
    size_t em_off = ((wt_off + (size_t)K_TOTAL * HID_C * 2 + 4095) / 4096) * 4096;
    unsigned* emeta = (unsigned*)((char*)d_ws + em_off);               // NN*16*4 B

    zero_count_kernel<<<1, 1, 0, stream>>>(count);

    long long tot = (long long)NN * 32;           // covers history copy
    if (tot < (long long)WE) tot = WE;
    prep_kernel<<<(int)((tot + 255) / 256), 256, 0, stream>>>(
        W, hmap, hbuf, ptr, idx, ety, Wt, list2, emeta, count, out, NN, WE);

    gemm_kernel<<<(NN + TILE_M - 1) / TILE_M, 256, 0, stream>>>(
        x, idx, ety, Wt, list2, emeta, count, out, NN);
}